// Round 12
// baseline (116.944 us; speedup 1.0000x reference)
//
#include <hip/hip_runtime.h>
#include <hip/hip_bf16.h>

// Problem constants: E=32768, K=32, D=128, H=4, dh=32, C=10
constexpr int E_EDGES = 32768;
constexpr int DIM = 128;

using bf16x8 = __attribute__((ext_vector_type(8))) short;   // MFMA A/B frag
using f32x4  = __attribute__((ext_vector_type(4))) float;   // MFMA C/D frag
using f32x2  = __attribute__((ext_vector_type(2))) float;
typedef unsigned int uint4v __attribute__((ext_vector_type(4)));
typedef unsigned int uint2v __attribute__((ext_vector_type(2)));

// bf16 (upper 16 bits of f32) unpack helpers
__device__ inline float bflo(unsigned u) { return __uint_as_float(u << 16); }
__device__ inline float bfhi(unsigned u) { return __uint_as_float(u & 0xffff0000u); }
__device__ inline f32x2 bf2f2(unsigned u) {
    f32x2 r;
    r[0] = __uint_as_float(u << 16);
    r[1] = __uint_as_float(u & 0xffff0000u);
    return r;
}
__device__ inline f32x2 fma2(f32x2 a, f32x2 b, f32x2 c) {
    return __builtin_elementwise_fma(a, b, c);   // -> v_pk_fma_f32
}
__device__ inline unsigned pk_bf2(float a, float b) {
    __hip_bfloat162 h = __float22bfloat162_rn(make_float2(a, b));
    return *(unsigned*)&h;
}

// Packed bf16 pair dot: s += a0*b0 + a1*b1 (v_dot2_f32_bf16 when available).
#if __has_builtin(__builtin_amdgcn_fdot2_f32_bf16)
typedef __bf16 bf16x2v __attribute__((ext_vector_type(2)));
__device__ inline float dot2bf(unsigned a, unsigned b, float c) {
    return __builtin_amdgcn_fdot2_f32_bf16(__builtin_bit_cast(bf16x2v, a),
                                           __builtin_bit_cast(bf16x2v, b),
                                           c, false);
}
#else
__device__ inline float dot2bf(unsigned a, unsigned b, float c) {
    float r = fmaf(bflo(a), bflo(b), c);
    return fmaf(bfhi(a), bfhi(b), r);
}
#endif

// ---------------------------------------------------------------------------
// Kernel P (grid=67): blocks 0-2: Wt[proj][n][k] = bf16(W_proj[k][n]).
// Blocks 3-66: Wf = Wo @ W1, stored transposed bf16: wft[n][k] = bf16(Wf[k][n]).
__global__ __launch_bounds__(256) void k_prep(
    const float* __restrict__ Wq, const float* __restrict__ Wk,
    const float* __restrict__ Wv, const float* __restrict__ Wo,
    const float* __restrict__ W1, __hip_bfloat16* __restrict__ Wt,
    __hip_bfloat16* __restrict__ wft) {
    const int b = blockIdx.x;
    const int t = threadIdx.x;
    if (b < 3) {
        const float* W = (b == 0) ? Wq : (b == 1) ? Wk : Wv;
        __hip_bfloat16* dst = Wt + b * 16384;
#pragma unroll
        for (int i = 0; i < 8; ++i) {
            int idx = i * 2048 + t * 8;
            int k = idx >> 7, n0 = idx & 127;
            float4 f0 = *(const float4*)(W + k * 128 + n0);
            float4 f1 = *(const float4*)(W + k * 128 + n0 + 4);
            float f[8] = {f0.x, f0.y, f0.z, f0.w, f1.x, f1.y, f1.z, f1.w};
#pragma unroll
            for (int j = 0; j < 8; ++j)
                dst[(n0 + j) * 128 + k] = __float2bfloat16(f[j]);
        }
    } else {
        int idx = (b - 3) * 256 + t;        // 0..16383
        int r = idx >> 7, c = idx & 127;    // Wf row r, col c
        float acc = 0.f;
#pragma unroll 16
        for (int k = 0; k < 128; ++k)
            acc = fmaf(Wo[r * 128 + k], W1[k * 128 + c], acc);
        wft[c * 128 + r] = __float2bfloat16(acc);
    }
}

// ---------------------------------------------------------------------------
// Kernel 1: QKV projection via bf16 MFMA. 128x128 tile per block, 4 waves
// (2x2, 64x64 each). A-frags loaded once, reused for all 3 projections.
// ALL outputs bf16 pair-major: xp[pr][e][64], head h -> pr=h&1,
// slot=((h>>1)<<5)+(dim&31).
__global__ __launch_bounds__(256) void k_qkv(
    const float* __restrict__ feats, const __hip_bfloat16* __restrict__ Wt,
    __hip_bfloat16* __restrict__ qp, __hip_bfloat16* __restrict__ kp,
    __hip_bfloat16* __restrict__ vp) {
    __shared__ short Als[16384];   // 128x128 bf16, swizzled: elem ^= (row&7)<<3
    __shared__ short Bls[16384];

    const int t = threadIdx.x;
    const int lane = t & 63;
    const int w = t >> 6;
    const int wm = w >> 1, wn = w & 1;
    const int row0 = blockIdx.x * 128;

#pragma unroll
    for (int i = 0; i < 8; ++i) {
        int idx = i * 2048 + t * 8;
        int r = idx >> 7, k0 = idx & 127;
        float4 f0 = *(const float4*)(feats + (size_t)(row0 + r) * DIM + k0);
        float4 f1 = *(const float4*)(feats + (size_t)(row0 + r) * DIM + k0 + 4);
        uint4 o = make_uint4(pk_bf2(f0.x, f0.y), pk_bf2(f0.z, f0.w),
                             pk_bf2(f1.x, f1.y), pk_bf2(f1.z, f1.w));
        *(uint4*)&Als[(r * 128 + k0) ^ ((r & 7) << 3)] = o;
    }
#pragma unroll
    for (int i = 0; i < 8; ++i) {
        int idx = i * 2048 + t * 8;
        int n = idx >> 7, k0 = idx & 127;
        uint4 v = *(const uint4*)(Wt + n * 128 + k0);
        *(uint4*)&Bls[(n * 128 + k0) ^ ((n & 7) << 3)] = v;
    }
    __syncthreads();

    bf16x8 afr[4][4];
#pragma unroll
    for (int m = 0; m < 4; ++m)
#pragma unroll
        for (int ks = 0; ks < 4; ++ks) {
            int r = wm * 64 + m * 16 + (lane & 15);
            int kb = ks * 32 + (lane >> 4) * 8;
            afr[m][ks] = *(bf16x8*)&Als[(r * 128 + kb) ^ ((r & 7) << 3)];
        }

    for (int proj = 0; proj < 3; ++proj) {
        f32x4 acc[4][4];
#pragma unroll
        for (int m = 0; m < 4; ++m)
#pragma unroll
            for (int n = 0; n < 4; ++n) acc[m][n] = (f32x4){0.f, 0.f, 0.f, 0.f};

#pragma unroll
        for (int ks = 0; ks < 4; ++ks) {
            bf16x8 bfr[4];
#pragma unroll
            for (int n = 0; n < 4; ++n) {
                int nn = wn * 64 + n * 16 + (lane & 15);
                int kb = ks * 32 + (lane >> 4) * 8;
                bfr[n] = *(bf16x8*)&Bls[(nn * 128 + kb) ^ ((nn & 7) << 3)];
            }
#pragma unroll
            for (int m = 0; m < 4; ++m)
#pragma unroll
                for (int n = 0; n < 4; ++n)
                    acc[m][n] = __builtin_amdgcn_mfma_f32_16x16x32_bf16(
                        afr[m][ks], bfr[n], acc[m][n], 0, 0, 0);
        }

        // Unified pair-major bf16 epilogue for q, k, v.
        {
            __hip_bfloat16* dst = (proj == 0) ? qp : (proj == 1) ? kp : vp;
#pragma unroll
            for (int n = 0; n < 4; ++n) {
                int c = wn * 64 + n * 16 + (lane & 15);
                int h = c >> 5, pr = h & 1;
                int slot = ((h >> 1) << 5) + (c & 31);
                size_t base = (size_t)pr * E_EDGES * 64 + slot;
#pragma unroll
                for (int m = 0; m < 4; ++m) {
                    int rb = row0 + wm * 64 + m * 16 + (lane >> 4) * 4;
#pragma unroll
                    for (int r = 0; r < 4; ++r)
                        dst[base + (size_t)(rb + r) * 64] =
                            __float2bfloat16(acc[m][n][r]);
                }
            }
        }

        if (proj < 2) {
            __syncthreads();
#pragma unroll
            for (int i = 0; i < 8; ++i) {
                int idx = i * 2048 + t * 8;
                int n = idx >> 7, k0 = idx & 127;
                uint4 v = *(const uint4*)(Wt + (proj + 1) * 16384 + n * 128 + k0);
                *(uint4*)&Bls[(n * 128 + k0) ^ ((n & 7) << 3)] = v;
            }
            __syncthreads();
        }
    }
}

// ---------------------------------------------------------------------------
// Kernel 2: FUSED attention + MLP per 16-edge tile. Grid = E/16 = 2048.
// Phase A: round-11 wave algorithm unchanged (zero block-LDS for attn data,
// shfl-only), 8 edge-pass units per wave; ctx written to LDS (bf16, swizzled)
// instead of HBM. Phase B: h = gelu(ctx @ Wf + b1) via 16x128x128 MFMA with
// A-frags from LDS ctx and B-frags read directly from L2-hot wft (no LDS
// staging); then logits = h @ W2 + b2 (160 outputs, f32 vector).
__global__ __launch_bounds__(256) void k_attn_mlp(
    const __hip_bfloat16* __restrict__ qp, const __hip_bfloat16* __restrict__ kp,
    const __hip_bfloat16* __restrict__ vp, const int* __restrict__ adj,
    const __hip_bfloat16* __restrict__ wft, const float* __restrict__ b1,
    const float* __restrict__ W2, const float* __restrict__ b2,
    float* __restrict__ out) {
    __shared__ short ctxls[2048];   // 16 x 128 bf16, swizzled ^((row&7)<<3)
    __shared__ short hls[2048];     // 16 x 128 bf16, swizzled
    __shared__ float w2s[1280];
    __shared__ float b1s[128];
    __shared__ float b2s[16];

    const int t = threadIdx.x;
    const int lane = t & 63;
    const int w = t >> 6;
    const int e0 = blockIdx.x * 16;

    for (int i = t; i < 1280; i += 256) w2s[i] = W2[i];
    if (t < 128) b1s[t] = b1[t];
    if (t < 10) b2s[t] = b2[t];

    // ---------------- Phase A: attention, 8 edge-pass units per wave -------
    const int n = lane & 31;
    const int g = lane >> 5;
    const int rsel = lane >> 3;        // PV neighbor sub-index
    const int csel = lane & 7;         // PV 16B col-block
    const int gi = csel >> 2;          // 0 -> head pass, 1 -> head pass+2

    for (int it = 0; it < 8; ++it) {
        const int u = w * 8 + it;      // 0..31
        const int pass = u >> 4;
        const int eloc = u & 15;
        const int e = e0 + eloc;

        int adjv = 0;
        if (lane < 32) adjv = __builtin_nontemporal_load(adj + e * 32 + lane);

        const uint4v* qr =
            (const uint4v*)(qp + ((size_t)pass * E_EDGES + e) * 64 + g * 32);
        uint4v qu[4];
#pragma unroll
        for (int j = 0; j < 4; ++j) qu[j] = __builtin_nontemporal_load(qr + j);

        const int row = __shfl(adjv, n, 64);
        const uint4* kr =
            (const uint4*)(kp + ((size_t)pass * E_EDGES + row) * 64 + g * 32);
        float s0 = 0.f;
#pragma unroll
        for (int j = 0; j < 4; ++j) {
            uint4 uu = kr[j];
            s0 = dot2bf(qu[j][0], uu.x, s0);
            s0 = dot2bf(qu[j][1], uu.y, s0);
            s0 = dot2bf(qu[j][2], uu.z, s0);
            s0 = dot2bf(qu[j][3], uu.w, s0);
        }
        s0 *= 0.17677669529663689f;   // 1/sqrt(32)

        float m0 = s0;
#pragma unroll
        for (int off = 16; off; off >>= 1) m0 = fmaxf(m0, __shfl_xor(m0, off));
        float ex0 = __expf(s0 - m0);
        float sum0 = ex0;
#pragma unroll
        for (int off = 16; off; off >>= 1) sum0 += __shfl_xor(sum0, off);
        const float wgt = ex0 / sum0;

        f32x2 c01 = {0.f, 0.f}, c23 = {0.f, 0.f}, c45 = {0.f, 0.f}, c67 = {0.f, 0.f};
#pragma unroll
        for (int i = 0; i < 4; ++i) {
            int nn = i * 8 + rsel;
            float a = __shfl(wgt, gi * 32 + nn, 64);
            int r2 = __shfl(adjv, nn, 64);
            uint4 uu = *(const uint4*)(vp + ((size_t)pass * E_EDGES + r2) * 64 + csel * 8);
            f32x2 a2 = {a, a};
            c01 = fma2(a2, bf2f2(uu.x), c01);
            c23 = fma2(a2, bf2f2(uu.y), c23);
            c45 = fma2(a2, bf2f2(uu.z), c45);
            c67 = fma2(a2, bf2f2(uu.w), c67);
        }
        float c[8] = {c01[0], c01[1], c23[0], c23[1], c45[0], c45[1], c67[0], c67[1]};
#pragma unroll
        for (int off = 8; off <= 32; off <<= 1)
#pragma unroll
            for (int j = 0; j < 8; ++j) c[j] += __shfl_xor(c[j], off);

        if (lane < 8) {
            int h2 = pass + 2 * (lane >> 2);
            uint4v o;
            o[0] = pk_bf2(c[0], c[1]);
            o[1] = pk_bf2(c[2], c[3]);
            o[2] = pk_bf2(c[4], c[5]);
            o[3] = pk_bf2(c[6], c[7]);
            *(uint4v*)&ctxls[(eloc * 128 + h2 * 32 + (lane & 3) * 8) ^
                             ((eloc & 7) << 3)] = o;
        }
    }
    __syncthreads();

    // ---------------- Phase B: h = gelu(ctx @ Wf + b1), MFMA 16x128x128 ----
    // Wave w handles output cols w*32 .. w*32+31 (2 n-frags).
    {
        const int lr = lane & 15;                 // A row (edge)
        bf16x8 afr[4], bfr[2][4];
#pragma unroll
        for (int ks = 0; ks < 4; ++ks) {
            int kb = ks * 32 + (lane >> 4) * 8;
            afr[ks] = *(bf16x8*)&ctxls[(lr * 128 + kb) ^ ((lr & 7) << 3)];
        }
#pragma unroll
        for (int nf = 0; nf < 2; ++nf)
#pragma unroll
            for (int ks = 0; ks < 4; ++ks) {
                int nn2 = w * 32 + nf * 16 + (lane & 15);
                int kb = ks * 32 + (lane >> 4) * 8;
                bfr[nf][ks] = *(const bf16x8*)(wft + nn2 * 128 + kb);
            }
        f32x4 acc[2] = {(f32x4){0.f, 0.f, 0.f, 0.f}, (f32x4){0.f, 0.f, 0.f, 0.f}};
#pragma unroll
        for (int ks = 0; ks < 4; ++ks) {
            acc[0] = __builtin_amdgcn_mfma_f32_16x16x32_bf16(afr[ks], bfr[0][ks],
                                                             acc[0], 0, 0, 0);
            acc[1] = __builtin_amdgcn_mfma_f32_16x16x32_bf16(afr[ks], bfr[1][ks],
                                                             acc[1], 0, 0, 0);
        }
#pragma unroll
        for (int nf = 0; nf < 2; ++nf) {
            int c = w * 32 + nf * 16 + (lane & 15);
            float bc = b1s[c];
#pragma unroll
            for (int r = 0; r < 4; ++r) {
                float x = acc[nf][r] + bc;
                float uu = 0.7978845608028654f * (x + 0.044715f * x * x * x);
                float exu = __expf(2.f * uu);
                float th = 1.f - 2.f / (exu + 1.f);
                float h = 0.5f * x * (1.f + th);
                int hr = (lane >> 4) * 4 + r;     // edge row
                hls[(hr * 128 + c) ^ ((hr & 7) << 3)] =
                    (short)(__bfloat16_as_ushort(__float2bfloat16(h)));
            }
        }
    }
    __syncthreads();

    // ---------------- logits: 16 edges x 10 classes = 160 outputs ----------
    if (t < 160) {
        int r = t / 10, c = t - r * 10;
        float a = b2s[c];
#pragma unroll 8
        for (int kk = 0; kk < 128; ++kk) {
            float hv = __uint_as_float(
                ((unsigned)(unsigned short)hls[(r * 128 + kk) ^ ((r & 7) << 3)]) << 16);
            a = fmaf(hv, w2s[kk * 10 + c], a);
        }
        out[(size_t)(e0 + r) * 10 + c] = a;
    }
}

// ---------------------------------------------------------------------------
extern "C" void kernel_launch(void* const* d_in, const int* in_sizes, int n_in,
                              void* d_out, int out_size, void* d_ws, size_t ws_size,
                              hipStream_t stream) {
    const float* feats = (const float*)d_in[0];
    const float* Wq    = (const float*)d_in[1];
    const float* Wk    = (const float*)d_in[2];
    const float* Wv    = (const float*)d_in[3];
    const float* Wo    = (const float*)d_in[4];
    const float* W1    = (const float*)d_in[5];
    const float* b1    = (const float*)d_in[6];
    const float* W2    = (const float*)d_in[7];
    const float* b2    = (const float*)d_in[8];
    const int*   adj   = (const int*)d_in[9];
    float* out = (float*)d_out;

    const size_t ED2 = (size_t)E_EDGES * 64;   // one pass-slice
    __hip_bfloat16* base = (__hip_bfloat16*)d_ws;
    __hip_bfloat16* qp   = base;               // [2][E][64] bf16 pair-major
    __hip_bfloat16* kp   = qp + 2 * ED2;       // [2][E][64]
    __hip_bfloat16* vp   = kp + 2 * ED2;       // [2][E][64]
    __hip_bfloat16* wt   = vp + 2 * ED2;       // 3*16384
    __hip_bfloat16* wft  = wt + 3 * 16384;     // 16384

    k_prep<<<67, 256, 0, stream>>>(Wq, Wk, Wv, Wo, W1, wt, wft);
    k_qkv<<<E_EDGES / 128, 256, 0, stream>>>(feats, wt, qp, kp, vp);
    k_attn_mlp<<<E_EDGES / 16, 256, 0, stream>>>(qp, kp, vp, adj, wft,
                                                 b1, W2, b2, out);
}

// Round 13
// 97.883 us; speedup vs baseline: 1.1947x; 1.1947x over previous
//
#include <hip/hip_runtime.h>
#include <hip/hip_bf16.h>

// Problem constants: E=32768, K=32, D=128, H=4, dh=32, C=10
constexpr int E_EDGES = 32768;
constexpr int DIM = 128;

using bf16x8 = __attribute__((ext_vector_type(8))) short;   // MFMA A/B frag
using f32x4  = __attribute__((ext_vector_type(4))) float;   // MFMA C/D frag
using f32x2  = __attribute__((ext_vector_type(2))) float;
typedef unsigned int uint4v __attribute__((ext_vector_type(4)));
typedef unsigned int uint2v __attribute__((ext_vector_type(2)));

// bf16 (upper 16 bits of f32) unpack helpers
__device__ inline float bflo(unsigned u) { return __uint_as_float(u << 16); }
__device__ inline float bfhi(unsigned u) { return __uint_as_float(u & 0xffff0000u); }
__device__ inline f32x2 bf2f2(unsigned u) {
    f32x2 r;
    r[0] = __uint_as_float(u << 16);
    r[1] = __uint_as_float(u & 0xffff0000u);
    return r;
}
__device__ inline f32x2 fma2(f32x2 a, f32x2 b, f32x2 c) {
    return __builtin_elementwise_fma(a, b, c);   // -> v_pk_fma_f32
}
__device__ inline unsigned pk_bf2(float a, float b) {
    __hip_bfloat162 h = __float22bfloat162_rn(make_float2(a, b));
    return *(unsigned*)&h;
}

// Packed bf16 pair dot: s += a0*b0 + a1*b1 (v_dot2_f32_bf16 when available).
#if __has_builtin(__builtin_amdgcn_fdot2_f32_bf16)
typedef __bf16 bf16x2v __attribute__((ext_vector_type(2)));
__device__ inline float dot2bf(unsigned a, unsigned b, float c) {
    return __builtin_amdgcn_fdot2_f32_bf16(__builtin_bit_cast(bf16x2v, a),
                                           __builtin_bit_cast(bf16x2v, b),
                                           c, false);
}
#else
__device__ inline float dot2bf(unsigned a, unsigned b, float c) {
    float r = fmaf(bflo(a), bflo(b), c);
    return fmaf(bfhi(a), bfhi(b), r);
}
#endif

// ---------------------------------------------------------------------------
// Kernel P (grid=67): blocks 0-2: Wt[proj][n][k] = bf16(W_proj[k][n]).
// Blocks 3-66: Wf = Wo @ W1, stored transposed bf16: wft[n][k] = bf16(Wf[k][n]).
__global__ __launch_bounds__(256) void k_prep(
    const float* __restrict__ Wq, const float* __restrict__ Wk,
    const float* __restrict__ Wv, const float* __restrict__ Wo,
    const float* __restrict__ W1, __hip_bfloat16* __restrict__ Wt,
    __hip_bfloat16* __restrict__ wft) {
    const int b = blockIdx.x;
    const int t = threadIdx.x;
    if (b < 3) {
        const float* W = (b == 0) ? Wq : (b == 1) ? Wk : Wv;
        __hip_bfloat16* dst = Wt + b * 16384;
#pragma unroll
        for (int i = 0; i < 8; ++i) {
            int idx = i * 2048 + t * 8;
            int k = idx >> 7, n0 = idx & 127;
            float4 f0 = *(const float4*)(W + k * 128 + n0);
            float4 f1 = *(const float4*)(W + k * 128 + n0 + 4);
            float f[8] = {f0.x, f0.y, f0.z, f0.w, f1.x, f1.y, f1.z, f1.w};
#pragma unroll
            for (int j = 0; j < 8; ++j)
                dst[(n0 + j) * 128 + k] = __float2bfloat16(f[j]);
        }
    } else {
        int idx = (b - 3) * 256 + t;        // 0..16383
        int r = idx >> 7, c = idx & 127;    // Wf row r, col c
        float acc = 0.f;
#pragma unroll 16
        for (int k = 0; k < 128; ++k)
            acc = fmaf(Wo[r * 128 + k], W1[k * 128 + c], acc);
        wft[c * 128 + r] = __float2bfloat16(acc);
    }
}

// ---------------------------------------------------------------------------
// Kernel 1: QKV projection via bf16 MFMA. 128x128 tile per block, 4 waves
// (2x2, 64x64 each). A-frags loaded once, reused for all 3 projections.
// Outputs bf16 pair-major xp[pr][e][64]. NEW: epilogue staged through the
// (free) Als LDS buffer, then stored with coalesced 16B/lane writes —
// replaces 64 scattered 2B stores/thread/proj with 8 vectorized ones.
__global__ __launch_bounds__(256) void k_qkv(
    const float* __restrict__ feats, const __hip_bfloat16* __restrict__ Wt,
    __hip_bfloat16* __restrict__ qp, __hip_bfloat16* __restrict__ kp,
    __hip_bfloat16* __restrict__ vp) {
    __shared__ short Als[16384];   // A tile, then per-proj output staging
    __shared__ short Bls[16384];

    const int t = threadIdx.x;
    const int lane = t & 63;
    const int w = t >> 6;
    const int wm = w >> 1, wn = w & 1;
    const int row0 = blockIdx.x * 128;

#pragma unroll
    for (int i = 0; i < 8; ++i) {
        int idx = i * 2048 + t * 8;
        int r = idx >> 7, k0 = idx & 127;
        float4 f0 = *(const float4*)(feats + (size_t)(row0 + r) * DIM + k0);
        float4 f1 = *(const float4*)(feats + (size_t)(row0 + r) * DIM + k0 + 4);
        uint4 o = make_uint4(pk_bf2(f0.x, f0.y), pk_bf2(f0.z, f0.w),
                             pk_bf2(f1.x, f1.y), pk_bf2(f1.z, f1.w));
        *(uint4*)&Als[(r * 128 + k0) ^ ((r & 7) << 3)] = o;
    }
#pragma unroll
    for (int i = 0; i < 8; ++i) {
        int idx = i * 2048 + t * 8;
        int n = idx >> 7, k0 = idx & 127;
        uint4 v = *(const uint4*)(Wt + n * 128 + k0);
        *(uint4*)&Bls[(n * 128 + k0) ^ ((n & 7) << 3)] = v;
    }
    __syncthreads();

    bf16x8 afr[4][4];
#pragma unroll
    for (int m = 0; m < 4; ++m)
#pragma unroll
        for (int ks = 0; ks < 4; ++ks) {
            int r = wm * 64 + m * 16 + (lane & 15);
            int kb = ks * 32 + (lane >> 4) * 8;
            afr[m][ks] = *(bf16x8*)&Als[(r * 128 + kb) ^ ((r & 7) << 3)];
        }

    for (int proj = 0; proj < 3; ++proj) {
        f32x4 acc[4][4];
#pragma unroll
        for (int m = 0; m < 4; ++m)
#pragma unroll
            for (int n = 0; n < 4; ++n) acc[m][n] = (f32x4){0.f, 0.f, 0.f, 0.f};

#pragma unroll
        for (int ks = 0; ks < 4; ++ks) {
            bf16x8 bfr[4];
#pragma unroll
            for (int n = 0; n < 4; ++n) {
                int nn = wn * 64 + n * 16 + (lane & 15);
                int kb = ks * 32 + (lane >> 4) * 8;
                bfr[n] = *(bf16x8*)&Bls[(nn * 128 + kb) ^ ((nn & 7) << 3)];
            }
#pragma unroll
            for (int m = 0; m < 4; ++m)
#pragma unroll
                for (int n = 0; n < 4; ++n)
                    acc[m][n] = __builtin_amdgcn_mfma_f32_16x16x32_bf16(
                        afr[m][ks], bfr[n], acc[m][n], 0, 0, 0);
        }

        // All waves done with Bls (this proj) and Als (frags in registers).
        __syncthreads();

        // Stage this proj's 128x128 bf16 output into Als, row-major swizzled.
#pragma unroll
        for (int m = 0; m < 4; ++m) {
#pragma unroll
            for (int n = 0; n < 4; ++n) {
                int c = wn * 64 + n * 16 + (lane & 15);
#pragma unroll
                for (int r = 0; r < 4; ++r) {
                    int lr = wm * 64 + m * 16 + (lane >> 4) * 4 + r;
                    Als[(lr * 128 + c) ^ ((lr & 7) << 3)] =
                        (short)__bfloat16_as_ushort(__float2bfloat16(acc[m][n][r]));
                }
            }
        }
        // Stage next proj's B while we're at it (overlaps the same barrier).
        if (proj < 2) {
#pragma unroll
            for (int i = 0; i < 8; ++i) {
                int idx = i * 2048 + t * 8;
                int n = idx >> 7, k0 = idx & 127;
                uint4 v = *(const uint4*)(Wt + (proj + 1) * 16384 + n * 128 + k0);
                *(uint4*)&Bls[(n * 128 + k0) ^ ((n & 7) << 3)] = v;
            }
        }
        __syncthreads();

        // Coalesced store: 16B per thread-iteration to the pair-major layout.
        {
            __hip_bfloat16* dst = (proj == 0) ? qp : (proj == 1) ? kp : vp;
#pragma unroll
            for (int i = 0; i < 8; ++i) {
                int id = i * 256 + t;            // 0..2047
                int r = id >> 4;                 // local row 0..127
                int c0 = (id & 15) * 8;          // col block 0,8,..,120
                uint4 v4 = *(uint4*)&Als[(r * 128 + c0) ^ ((r & 7) << 3)];
                int h = c0 >> 5, pr = h & 1;
                int slot = ((h >> 1) << 5) + (c0 & 31);
                *(uint4*)(dst + ((size_t)pr * E_EDGES + row0 + r) * 64 + slot) = v4;
            }
        }
    }
}

// ---------------------------------------------------------------------------
// Kernel 2: fused edge attention, pass = blockIdx.y. ZERO LDS: adj and
// softmax weights move between phases via __shfl (wave-synchronous).
// Score keeps q/k fully packed via v_dot2_f32_bf16 (no unpack insts).
// PV: lane owns 16B of the 128B pair-row (rsel=l>>3 picks neighbor-subset,
// csel=l&7 the col-block), 4x uint4 loads, packed f32x2 FMA, xor-8/16/32
// reduce. One 64-lane wave per edge; 4 edges per block.
__global__ __launch_bounds__(256) void k_attn(
    const __hip_bfloat16* __restrict__ qp, const __hip_bfloat16* __restrict__ kp,
    const __hip_bfloat16* __restrict__ vp, const int* __restrict__ adj,
    __hip_bfloat16* __restrict__ ctxb) {
    const int pass = blockIdx.y;
    const int lane = threadIdx.x & 63;
    const int e = blockIdx.x * 4 + (threadIdx.x >> 6);
    const int n = lane & 31;
    const int g = lane >> 5;

    // adj row for this edge: lanes 0..31 hold adj[e][lane].
    int adjv = 0;
    if (lane < 32) adjv = __builtin_nontemporal_load(adj + e * 32 + lane);

    // q slice for head pass+2g (32 bf16 = 16 packed pairs), kept packed.
    const uint4v* qr =
        (const uint4v*)(qp + ((size_t)pass * E_EDGES + e) * 64 + g * 32);
    uint4v qu[4];
#pragma unroll
    for (int j = 0; j < 4; ++j) qu[j] = __builtin_nontemporal_load(qr + j);

    // k gather: one contiguous 128B slice per (neighbor n, pair-slot g).
    const int row = __shfl(adjv, n, 64);
    const uint4* kr =
        (const uint4*)(kp + ((size_t)pass * E_EDGES + row) * 64 + g * 32);
    float s0 = 0.f;
#pragma unroll
    for (int j = 0; j < 4; ++j) {
        uint4 u = kr[j];
        s0 = dot2bf(qu[j][0], u.x, s0);
        s0 = dot2bf(qu[j][1], u.y, s0);
        s0 = dot2bf(qu[j][2], u.z, s0);
        s0 = dot2bf(qu[j][3], u.w, s0);
    }
    s0 *= 0.17677669529663689f;   // 1/sqrt(32)

    // Softmax over n within each 32-lane half.
    float m0 = s0;
#pragma unroll
    for (int off = 16; off; off >>= 1) m0 = fmaxf(m0, __shfl_xor(m0, off));
    float e0 = __expf(s0 - m0);
    float sum0 = e0;
#pragma unroll
    for (int off = 16; off; off >>= 1) sum0 += __shfl_xor(sum0, off);
    const float wgt = e0 / sum0;   // weight for (pair-slot g, neighbor n)

    // ---- PV: lane owns 16B (8 bf16 cols) of the 128B pair-row ----
    const int rsel = lane >> 3;        // neighbor sub-index
    const int csel = lane & 7;         // 16B col-block: cols csel*8..+7
    const int gi = csel >> 2;          // 0 -> head pass, 1 -> head pass+2
    f32x2 c01 = {0.f, 0.f}, c23 = {0.f, 0.f}, c45 = {0.f, 0.f}, c67 = {0.f, 0.f};
#pragma unroll
    for (int i = 0; i < 4; ++i) {
        int nn = i * 8 + rsel;
        float a = __shfl(wgt, gi * 32 + nn, 64);
        int r2 = __shfl(adjv, nn, 64);
        uint4 u = *(const uint4*)(vp + ((size_t)pass * E_EDGES + r2) * 64 + csel * 8);
        f32x2 a2 = {a, a};
        c01 = fma2(a2, bf2f2(u.x), c01);
        c23 = fma2(a2, bf2f2(u.y), c23);
        c45 = fma2(a2, bf2f2(u.z), c45);
        c67 = fma2(a2, bf2f2(u.w), c67);
    }
    float c[8] = {c01[0], c01[1], c23[0], c23[1], c45[0], c45[1], c67[0], c67[1]};
#pragma unroll
    for (int off = 8; off <= 32; off <<= 1)
#pragma unroll
        for (int j = 0; j < 8; ++j) c[j] += __shfl_xor(c[j], off);

    if (lane < 8) {
        int h2 = pass + 2 * (lane >> 2);   // gi for rsel==0 lanes
        uint4v o;
        o[0] = pk_bf2(c[0], c[1]);
        o[1] = pk_bf2(c[2], c[3]);
        o[2] = pk_bf2(c[4], c[5]);
        o[3] = pk_bf2(c[6], c[7]);
        __builtin_nontemporal_store(
            o, (uint4v*)(ctxb + (size_t)e * DIM + h2 * 32 + (lane & 3) * 8));
    }
}

// ---------------------------------------------------------------------------
// Kernel 3: MLP via bf16 MFMA. h = gelu_tanh(ctx @ Wf + b1) with MFMA,
// h re-staged bf16 in LDS, logits = h @ W2 + b2 (f32 vector).
__global__ __launch_bounds__(256) void k_mlp(
    const __hip_bfloat16* __restrict__ ctxb, const __hip_bfloat16* __restrict__ wft,
    const float* __restrict__ b1, const float* __restrict__ W2,
    const float* __restrict__ b2, float* __restrict__ out) {
    __shared__ short Als[16384];   // A tile, then reused for h (bf16, swizzled)
    __shared__ short Bls[16384];
    __shared__ float w2s[1280];
    __shared__ float b1s[128];
    __shared__ float b2s[16];

    const int t = threadIdx.x;
    const int lane = t & 63;
    const int w = t >> 6;
    const int wm = w >> 1, wn = w & 1;
    const int row0 = blockIdx.x * 128;

#pragma unroll
    for (int i = 0; i < 8; ++i) {
        int idx = i * 2048 + t * 8;
        int r = idx >> 7, k0 = idx & 127;
        uint4 v = *(const uint4*)(ctxb + (size_t)(row0 + r) * DIM + k0);
        *(uint4*)&Als[(r * 128 + k0) ^ ((r & 7) << 3)] = v;
    }
#pragma unroll
    for (int i = 0; i < 8; ++i) {
        int idx = i * 2048 + t * 8;
        int n = idx >> 7, k0 = idx & 127;
        uint4 v = *(const uint4*)(wft + n * 128 + k0);
        *(uint4*)&Bls[(n * 128 + k0) ^ ((n & 7) << 3)] = v;
    }
    for (int i = t; i < 1280; i += 256) w2s[i] = W2[i];
    if (t < 128) b1s[t] = b1[t];
    if (t < 10) b2s[t] = b2[t];
    __syncthreads();

    f32x4 acc[4][4];
#pragma unroll
    for (int m = 0; m < 4; ++m)
#pragma unroll
        for (int n = 0; n < 4; ++n) acc[m][n] = (f32x4){0.f, 0.f, 0.f, 0.f};

#pragma unroll
    for (int ks = 0; ks < 4; ++ks) {
        bf16x8 afr[4], bfr[4];
#pragma unroll
        for (int m = 0; m < 4; ++m) {
            int r = wm * 64 + m * 16 + (lane & 15);
            int kb = ks * 32 + (lane >> 4) * 8;
            afr[m] = *(bf16x8*)&Als[(r * 128 + kb) ^ ((r & 7) << 3)];
        }
#pragma unroll
        for (int n = 0; n < 4; ++n) {
            int nn = wn * 64 + n * 16 + (lane & 15);
            int kb = ks * 32 + (lane >> 4) * 8;
            bfr[n] = *(bf16x8*)&Bls[(nn * 128 + kb) ^ ((nn & 7) << 3)];
        }
#pragma unroll
        for (int m = 0; m < 4; ++m)
#pragma unroll
            for (int n = 0; n < 4; ++n)
                acc[m][n] = __builtin_amdgcn_mfma_f32_16x16x32_bf16(
                    afr[m], bfr[n], acc[m][n], 0, 0, 0);
    }

    __syncthreads();   // done reading Als; reuse it for h
#pragma unroll
    for (int m = 0; m < 4; ++m) {
        int lr0 = wm * 64 + m * 16 + (lane >> 4) * 4;
#pragma unroll
        for (int n = 0; n < 4; ++n) {
            int c = wn * 64 + n * 16 + (lane & 15);
            float bc = b1s[c];
#pragma unroll
            for (int r = 0; r < 4; ++r) {
                float x = acc[m][n][r] + bc;
                float u = 0.7978845608028654f * (x + 0.044715f * x * x * x);
                float ex = __expf(2.f * u);
                float th = 1.f - 2.f / (ex + 1.f);
                float h = 0.5f * x * (1.f + th);
                int lr = lr0 + r;
                Als[(lr * 128 + c) ^ ((lr & 7) << 3)] =
                    (short)(__bfloat16_as_ushort(__float2bfloat16(h)));
            }
        }
    }
    __syncthreads();

    {
        int r = t >> 1;
        int c0 = (t & 1) * 5;
        float a0 = b2s[c0], a1 = b2s[c0 + 1], a2 = b2s[c0 + 2],
              a3 = b2s[c0 + 3], a4 = b2s[c0 + 4];
#pragma unroll 8
        for (int kk = 0; kk < 128; ++kk) {
            float hv = __uint_as_float(
                ((unsigned)(unsigned short)Als[(r * 128 + kk) ^ ((r & 7) << 3)]) << 16);
            const float* wrow = &w2s[kk * 10 + c0];
            a0 = fmaf(hv, wrow[0], a0);
            a1 = fmaf(hv, wrow[1], a1);
            a2 = fmaf(hv, wrow[2], a2);
            a3 = fmaf(hv, wrow[3], a3);
            a4 = fmaf(hv, wrow[4], a4);
        }
        float* o = out + (size_t)(row0 + r) * 10 + c0;
        o[0] = a0; o[1] = a1; o[2] = a2; o[3] = a3; o[4] = a4;
    }
}

// ---------------------------------------------------------------------------
extern "C" void kernel_launch(void* const* d_in, const int* in_sizes, int n_in,
                              void* d_out, int out_size, void* d_ws, size_t ws_size,
                              hipStream_t stream) {
    const float* feats = (const float*)d_in[0];
    const float* Wq    = (const float*)d_in[1];
    const float* Wk    = (const float*)d_in[2];
    const float* Wv    = (const float*)d_in[3];
    const float* Wo    = (const float*)d_in[4];
    const float* W1    = (const float*)d_in[5];
    const float* b1    = (const float*)d_in[6];
    const float* W2    = (const float*)d_in[7];
    const float* b2    = (const float*)d_in[8];
    const int*   adj   = (const int*)d_in[9];
    float* out = (float*)d_out;

    const size_t ED2 = (size_t)E_EDGES * 64;   // one pass-slice
    __hip_bfloat16* base = (__hip_bfloat16*)d_ws;
    __hip_bfloat16* qp   = base;               // [2][E][64] bf16 pair-major
    __hip_bfloat16* kp   = qp + 2 * ED2;       // [2][E][64]
    __hip_bfloat16* vp   = kp + 2 * ED2;       // [2][E][64]
    __hip_bfloat16* ctxb = vp + 2 * ED2;       // [E][128]
    __hip_bfloat16* wt   = ctxb + 2 * ED2;     // 3*16384
    __hip_bfloat16* wft  = wt + 3 * 16384;     // 16384

    k_prep<<<67, 256, 0, stream>>>(Wq, Wk, Wv, Wo, W1, wt, wft);
    k_qkv<<<E_EDGES / 128, 256, 0, stream>>>(feats, wt, qp, kp, vp);
    k_attn<<<dim3(E_EDGES / 4, 2), 256, 0, stream>>>(qp, kp, vp, adj, ctxb);
    k_mlp<<<E_EDGES / 128, 256, 0, stream>>>(ctxb, wft, b1, W2, b2, out);
}

// Round 14
// 96.867 us; speedup vs baseline: 1.2073x; 1.0105x over previous
//
#include <hip/hip_runtime.h>
#include <hip/hip_bf16.h>

// Problem constants: E=32768, K=32, D=128, H=4, dh=32, C=10
constexpr int E_EDGES = 32768;
constexpr int DIM = 128;

using bf16x8 = __attribute__((ext_vector_type(8))) short;   // MFMA A/B frag
using f32x4  = __attribute__((ext_vector_type(4))) float;   // MFMA C/D frag
using f32x2  = __attribute__((ext_vector_type(2))) float;
typedef unsigned int uint4v __attribute__((ext_vector_type(4)));
typedef unsigned int uint2v __attribute__((ext_vector_type(2)));

// bf16 (upper 16 bits of f32) unpack helpers
__device__ inline float bflo(unsigned u) { return __uint_as_float(u << 16); }
__device__ inline float bfhi(unsigned u) { return __uint_as_float(u & 0xffff0000u); }
__device__ inline f32x2 bf2f2(unsigned u) {
    f32x2 r;
    r[0] = __uint_as_float(u << 16);
    r[1] = __uint_as_float(u & 0xffff0000u);
    return r;
}
__device__ inline f32x2 fma2(f32x2 a, f32x2 b, f32x2 c) {
    return __builtin_elementwise_fma(a, b, c);   // -> v_pk_fma_f32
}
__device__ inline unsigned pk_bf2(float a, float b) {
    __hip_bfloat162 h = __float22bfloat162_rn(make_float2(a, b));
    return *(unsigned*)&h;
}

// Packed bf16 pair dot: s += a0*b0 + a1*b1 (v_dot2_f32_bf16 when available).
#if __has_builtin(__builtin_amdgcn_fdot2_f32_bf16)
typedef __bf16 bf16x2v __attribute__((ext_vector_type(2)));
__device__ inline float dot2bf(unsigned a, unsigned b, float c) {
    return __builtin_amdgcn_fdot2_f32_bf16(__builtin_bit_cast(bf16x2v, a),
                                           __builtin_bit_cast(bf16x2v, b),
                                           c, false);
}
#else
__device__ inline float dot2bf(unsigned a, unsigned b, float c) {
    float r = fmaf(bflo(a), bflo(b), c);
    return fmaf(bfhi(a), bfhi(b), r);
}
#endif

// ---------------------------------------------------------------------------
// Kernel P (grid=67): blocks 0-2: Wt[proj][n][k] = bf16(W_proj[k][n]).
// Blocks 3-66: Wf = Wo @ W1, stored transposed bf16: wft[n][k] = bf16(Wf[k][n]).
__global__ __launch_bounds__(256) void k_prep(
    const float* __restrict__ Wq, const float* __restrict__ Wk,
    const float* __restrict__ Wv, const float* __restrict__ Wo,
    const float* __restrict__ W1, __hip_bfloat16* __restrict__ Wt,
    __hip_bfloat16* __restrict__ wft) {
    const int b = blockIdx.x;
    const int t = threadIdx.x;
    if (b < 3) {
        const float* W = (b == 0) ? Wq : (b == 1) ? Wk : Wv;
        __hip_bfloat16* dst = Wt + b * 16384;
#pragma unroll
        for (int i = 0; i < 8; ++i) {
            int idx = i * 2048 + t * 8;
            int k = idx >> 7, n0 = idx & 127;
            float4 f0 = *(const float4*)(W + k * 128 + n0);
            float4 f1 = *(const float4*)(W + k * 128 + n0 + 4);
            float f[8] = {f0.x, f0.y, f0.z, f0.w, f1.x, f1.y, f1.z, f1.w};
#pragma unroll
            for (int j = 0; j < 8; ++j)
                dst[(n0 + j) * 128 + k] = __float2bfloat16(f[j]);
        }
    } else {
        int idx = (b - 3) * 256 + t;        // 0..16383
        int r = idx >> 7, c = idx & 127;    // Wf row r, col c
        float acc = 0.f;
#pragma unroll 16
        for (int k = 0; k < 128; ++k)
            acc = fmaf(Wo[r * 128 + k], W1[k * 128 + c], acc);
        wft[c * 128 + r] = __float2bfloat16(acc);
    }
}

// ---------------------------------------------------------------------------
// Kernel 1: QKV projection via bf16 MFMA. BM=64 tile per block -> 512 blocks
// (2 blocks/CU, 8 waves/CU — 2x the occupancy of the BM=128 version).
// 4 waves (2x2), each 32 rows x 64 cols. A-frags loaded once, reused for all
// 3 projections. Outputs bf16 pair-major xp[pr][e][64]; epilogue staged via
// LDS then stored with coalesced 16B writes.
__global__ __launch_bounds__(256) void k_qkv(
    const float* __restrict__ feats, const __hip_bfloat16* __restrict__ Wt,
    __hip_bfloat16* __restrict__ qp, __hip_bfloat16* __restrict__ kp,
    __hip_bfloat16* __restrict__ vp) {
    __shared__ short Als[8192];    // 64x128 bf16, swizzled: elem ^= (row&7)<<3
    __shared__ short Bls[16384];   // 128(n) x 128(k) bf16, swizzled

    const int t = threadIdx.x;
    const int lane = t & 63;
    const int w = t >> 6;
    const int wm = w >> 1, wn = w & 1;   // wave tile: 32 rows x 64 cols
    const int row0 = blockIdx.x * 64;

    // Stage A tile (64x128): coalesced f32 reads, cvt bf16, swizzled writes.
#pragma unroll
    for (int i = 0; i < 4; ++i) {
        int idx = (i * 256 + t) * 8;
        int r = idx >> 7, k0 = idx & 127;
        float4 f0 = *(const float4*)(feats + (size_t)(row0 + r) * DIM + k0);
        float4 f1 = *(const float4*)(feats + (size_t)(row0 + r) * DIM + k0 + 4);
        uint4 o = make_uint4(pk_bf2(f0.x, f0.y), pk_bf2(f0.z, f0.w),
                             pk_bf2(f1.x, f1.y), pk_bf2(f1.z, f1.w));
        *(uint4*)&Als[(r * 128 + k0) ^ ((r & 7) << 3)] = o;
    }
    // Stage B for proj 0.
#pragma unroll
    for (int i = 0; i < 8; ++i) {
        int idx = i * 2048 + t * 8;
        int n = idx >> 7, k0 = idx & 127;
        uint4 v = *(const uint4*)(Wt + n * 128 + k0);
        *(uint4*)&Bls[(n * 128 + k0) ^ ((n & 7) << 3)] = v;
    }
    __syncthreads();

    // A-frags into registers once (reused across all 3 projections).
    bf16x8 afr[2][4];
#pragma unroll
    for (int m = 0; m < 2; ++m)
#pragma unroll
        for (int ks = 0; ks < 4; ++ks) {
            int r = wm * 32 + m * 16 + (lane & 15);
            int kb = ks * 32 + (lane >> 4) * 8;
            afr[m][ks] = *(bf16x8*)&Als[(r * 128 + kb) ^ ((r & 7) << 3)];
        }

    for (int proj = 0; proj < 3; ++proj) {
        f32x4 acc[2][4];
#pragma unroll
        for (int m = 0; m < 2; ++m)
#pragma unroll
            for (int n = 0; n < 4; ++n) acc[m][n] = (f32x4){0.f, 0.f, 0.f, 0.f};

#pragma unroll
        for (int ks = 0; ks < 4; ++ks) {
            bf16x8 bfr[4];
#pragma unroll
            for (int n = 0; n < 4; ++n) {
                int nn = wn * 64 + n * 16 + (lane & 15);
                int kb = ks * 32 + (lane >> 4) * 8;
                bfr[n] = *(bf16x8*)&Bls[(nn * 128 + kb) ^ ((nn & 7) << 3)];
            }
#pragma unroll
            for (int m = 0; m < 2; ++m)
#pragma unroll
                for (int n = 0; n < 4; ++n)
                    acc[m][n] = __builtin_amdgcn_mfma_f32_16x16x32_bf16(
                        afr[m][ks], bfr[n], acc[m][n], 0, 0, 0);
        }

        __syncthreads();   // Bls/Als reads done (frags in registers)

        // Stage this proj's 64x128 bf16 output into Als (swizzled).
#pragma unroll
        for (int m = 0; m < 2; ++m) {
#pragma unroll
            for (int n = 0; n < 4; ++n) {
                int c = wn * 64 + n * 16 + (lane & 15);
#pragma unroll
                for (int r = 0; r < 4; ++r) {
                    int lr = wm * 32 + m * 16 + (lane >> 4) * 4 + r;
                    Als[(lr * 128 + c) ^ ((lr & 7) << 3)] =
                        (short)__bfloat16_as_ushort(__float2bfloat16(acc[m][n][r]));
                }
            }
        }
        if (proj < 2) {   // stage next proj's B under the same barrier
#pragma unroll
            for (int i = 0; i < 8; ++i) {
                int idx = i * 2048 + t * 8;
                int n = idx >> 7, k0 = idx & 127;
                uint4 v = *(const uint4*)(Wt + (proj + 1) * 16384 + n * 128 + k0);
                *(uint4*)&Bls[(n * 128 + k0) ^ ((n & 7) << 3)] = v;
            }
        }
        __syncthreads();

        // Coalesced store to pair-major layout: 16B per thread-iteration.
        {
            __hip_bfloat16* dst = (proj == 0) ? qp : (proj == 1) ? kp : vp;
#pragma unroll
            for (int i = 0; i < 4; ++i) {
                int id = i * 256 + t;            // 0..1023
                int r = id >> 4;                 // local row 0..63
                int c0 = (id & 15) * 8;          // col block 0,8,..,120
                uint4 v4 = *(uint4*)&Als[(r * 128 + c0) ^ ((r & 7) << 3)];
                int h = c0 >> 5, pr = h & 1;
                int slot = ((h >> 1) << 5) + (c0 & 31);
                *(uint4*)(dst + ((size_t)pr * E_EDGES + row0 + r) * 64 + slot) = v4;
            }
        }
    }
}

// ---------------------------------------------------------------------------
// Kernel 2: fused edge attention, pass = blockIdx.y. ZERO LDS (shfl-only),
// packed dot2 score, 16B-per-lane PV. Unchanged from round 11 (proven).
__global__ __launch_bounds__(256) void k_attn(
    const __hip_bfloat16* __restrict__ qp, const __hip_bfloat16* __restrict__ kp,
    const __hip_bfloat16* __restrict__ vp, const int* __restrict__ adj,
    __hip_bfloat16* __restrict__ ctxb) {
    const int pass = blockIdx.y;
    const int lane = threadIdx.x & 63;
    const int e = blockIdx.x * 4 + (threadIdx.x >> 6);
    const int n = lane & 31;
    const int g = lane >> 5;

    int adjv = 0;
    if (lane < 32) adjv = __builtin_nontemporal_load(adj + e * 32 + lane);

    const uint4v* qr =
        (const uint4v*)(qp + ((size_t)pass * E_EDGES + e) * 64 + g * 32);
    uint4v qu[4];
#pragma unroll
    for (int j = 0; j < 4; ++j) qu[j] = __builtin_nontemporal_load(qr + j);

    const int row = __shfl(adjv, n, 64);
    const uint4* kr =
        (const uint4*)(kp + ((size_t)pass * E_EDGES + row) * 64 + g * 32);
    float s0 = 0.f;
#pragma unroll
    for (int j = 0; j < 4; ++j) {
        uint4 u = kr[j];
        s0 = dot2bf(qu[j][0], u.x, s0);
        s0 = dot2bf(qu[j][1], u.y, s0);
        s0 = dot2bf(qu[j][2], u.z, s0);
        s0 = dot2bf(qu[j][3], u.w, s0);
    }
    s0 *= 0.17677669529663689f;   // 1/sqrt(32)

    float m0 = s0;
#pragma unroll
    for (int off = 16; off; off >>= 1) m0 = fmaxf(m0, __shfl_xor(m0, off));
    float e0 = __expf(s0 - m0);
    float sum0 = e0;
#pragma unroll
    for (int off = 16; off; off >>= 1) sum0 += __shfl_xor(sum0, off);
    const float wgt = e0 / sum0;

    const int rsel = lane >> 3;
    const int csel = lane & 7;
    const int gi = csel >> 2;
    f32x2 c01 = {0.f, 0.f}, c23 = {0.f, 0.f}, c45 = {0.f, 0.f}, c67 = {0.f, 0.f};
#pragma unroll
    for (int i = 0; i < 4; ++i) {
        int nn = i * 8 + rsel;
        float a = __shfl(wgt, gi * 32 + nn, 64);
        int r2 = __shfl(adjv, nn, 64);
        uint4 u = *(const uint4*)(vp + ((size_t)pass * E_EDGES + r2) * 64 + csel * 8);
        f32x2 a2 = {a, a};
        c01 = fma2(a2, bf2f2(u.x), c01);
        c23 = fma2(a2, bf2f2(u.y), c23);
        c45 = fma2(a2, bf2f2(u.z), c45);
        c67 = fma2(a2, bf2f2(u.w), c67);
    }
    float c[8] = {c01[0], c01[1], c23[0], c23[1], c45[0], c45[1], c67[0], c67[1]};
#pragma unroll
    for (int off = 8; off <= 32; off <<= 1)
#pragma unroll
        for (int j = 0; j < 8; ++j) c[j] += __shfl_xor(c[j], off);

    if (lane < 8) {
        int h2 = pass + 2 * (lane >> 2);
        uint4v o;
        o[0] = pk_bf2(c[0], c[1]);
        o[1] = pk_bf2(c[2], c[3]);
        o[2] = pk_bf2(c[4], c[5]);
        o[3] = pk_bf2(c[6], c[7]);
        __builtin_nontemporal_store(
            o, (uint4v*)(ctxb + (size_t)e * DIM + h2 * 32 + (lane & 3) * 8));
    }
}

// ---------------------------------------------------------------------------
// Kernel 3: MLP via bf16 MFMA. BM=64 -> 512 blocks (2 blocks/CU).
// h = gelu_tanh(ctx @ Wf + b1), h re-staged bf16 in LDS, logits f32 vector.
__global__ __launch_bounds__(256) void k_mlp(
    const __hip_bfloat16* __restrict__ ctxb, const __hip_bfloat16* __restrict__ wft,
    const float* __restrict__ b1, const float* __restrict__ W2,
    const float* __restrict__ b2, float* __restrict__ out) {
    __shared__ short Als[8192];    // 64x128 A tile, then reused for h
    __shared__ short Bls[16384];
    __shared__ float w2s[1280];
    __shared__ float b1s[128];
    __shared__ float b2s[16];

    const int t = threadIdx.x;
    const int lane = t & 63;
    const int w = t >> 6;
    const int wm = w >> 1, wn = w & 1;   // wave tile: 32 rows x 64 cols
    const int row0 = blockIdx.x * 64;

#pragma unroll
    for (int i = 0; i < 4; ++i) {
        int idx = (i * 256 + t) * 8;
        int r = idx >> 7, k0 = idx & 127;
        uint4 v = *(const uint4*)(ctxb + (size_t)(row0 + r) * DIM + k0);
        *(uint4*)&Als[(r * 128 + k0) ^ ((r & 7) << 3)] = v;
    }
#pragma unroll
    for (int i = 0; i < 8; ++i) {
        int idx = i * 2048 + t * 8;
        int n = idx >> 7, k0 = idx & 127;
        uint4 v = *(const uint4*)(wft + n * 128 + k0);
        *(uint4*)&Bls[(n * 128 + k0) ^ ((n & 7) << 3)] = v;
    }
    for (int i = t; i < 1280; i += 256) w2s[i] = W2[i];
    if (t < 128) b1s[t] = b1[t];
    if (t < 10) b2s[t] = b2[t];
    __syncthreads();

    f32x4 acc[2][4];
#pragma unroll
    for (int m = 0; m < 2; ++m)
#pragma unroll
        for (int n = 0; n < 4; ++n) acc[m][n] = (f32x4){0.f, 0.f, 0.f, 0.f};

#pragma unroll
    for (int ks = 0; ks < 4; ++ks) {
        bf16x8 afr[2], bfr[4];
#pragma unroll
        for (int m = 0; m < 2; ++m) {
            int r = wm * 32 + m * 16 + (lane & 15);
            int kb = ks * 32 + (lane >> 4) * 8;
            afr[m] = *(bf16x8*)&Als[(r * 128 + kb) ^ ((r & 7) << 3)];
        }
#pragma unroll
        for (int n = 0; n < 4; ++n) {
            int nn = wn * 64 + n * 16 + (lane & 15);
            int kb = ks * 32 + (lane >> 4) * 8;
            bfr[n] = *(bf16x8*)&Bls[(nn * 128 + kb) ^ ((nn & 7) << 3)];
        }
#pragma unroll
        for (int m = 0; m < 2; ++m)
#pragma unroll
            for (int n = 0; n < 4; ++n)
                acc[m][n] = __builtin_amdgcn_mfma_f32_16x16x32_bf16(
                    afr[m], bfr[n], acc[m][n], 0, 0, 0);
    }

    __syncthreads();   // done reading Als; reuse it for h
#pragma unroll
    for (int m = 0; m < 2; ++m) {
        int lr0 = wm * 32 + m * 16 + (lane >> 4) * 4;
#pragma unroll
        for (int n = 0; n < 4; ++n) {
            int c = wn * 64 + n * 16 + (lane & 15);
            float bc = b1s[c];
#pragma unroll
            for (int r = 0; r < 4; ++r) {
                float x = acc[m][n][r] + bc;
                float u = 0.7978845608028654f * (x + 0.044715f * x * x * x);
                float ex = __expf(2.f * u);
                float th = 1.f - 2.f / (ex + 1.f);
                float h = 0.5f * x * (1.f + th);
                int lr = lr0 + r;
                Als[(lr * 128 + c) ^ ((lr & 7) << 3)] =
                    (short)(__bfloat16_as_ushort(__float2bfloat16(h)));
            }
        }
    }
    __syncthreads();

    // logits: 64 rows x 10 classes = 640 outputs.
    for (int idx = t; idx < 640; idx += 256) {
        int r = idx / 10, c = idx - r * 10;
        float a = b2s[c];
#pragma unroll 8
        for (int kk = 0; kk < 128; ++kk) {
            float hv = __uint_as_float(
                ((unsigned)(unsigned short)Als[(r * 128 + kk) ^ ((r & 7) << 3)]) << 16);
            a = fmaf(hv, w2s[kk * 10 + c], a);
        }
        out[(size_t)(row0 + r) * 10 + c] = a;
    }
}

// ---------------------------------------------------------------------------
extern "C" void kernel_launch(void* const* d_in, const int* in_sizes, int n_in,
                              void* d_out, int out_size, void* d_ws, size_t ws_size,
                              hipStream_t stream) {
    const float* feats = (const float*)d_in[0];
    const float* Wq    = (const float*)d_in[1];
    const float* Wk    = (const float*)d_in[2];
    const float* Wv    = (const float*)d_in[3];
    const float* Wo    = (const float*)d_in[4];
    const float* W1    = (const float*)d_in[5];
    const float* b1    = (const float*)d_in[6];
    const float* W2    = (const float*)d_in[7];
    const float* b2    = (const float*)d_in[8];
    const int*   adj   = (const int*)d_in[9];
    float* out = (float*)d_out;

    const size_t ED2 = (size_t)E_EDGES * 64;   // one pass-slice
    __hip_bfloat16* base = (__hip_bfloat16*)d_ws;
    __hip_bfloat16* qp   = base;               // [2][E][64] bf16 pair-major
    __hip_bfloat16* kp   = qp + 2 * ED2;       // [2][E][64]
    __hip_bfloat16* vp   = kp + 2 * ED2;       // [2][E][64]
    __hip_bfloat16* ctxb = vp + 2 * ED2;       // [E][128]
    __hip_bfloat16* wt   = ctxb + 2 * ED2;     // 3*16384
    __hip_bfloat16* wft  = wt + 3 * 16384;     // 16384

    k_prep<<<67, 256, 0, stream>>>(Wq, Wk, Wv, Wo, W1, wt, wft);
    k_qkv<<<E_EDGES / 64, 256, 0, stream>>>(feats, wt, qp, kp, vp);
    k_attn<<<dim3(E_EDGES / 4, 2), 256, 0, stream>>>(qp, kp, vp, adj, ctxb);
    k_mlp<<<E_EDGES / 64, 256, 0, stream>>>(ctxb, wft, b1, W2, b2, out);
}